// Round 1
// baseline (605.673 us; speedup 1.0000x reference)
//
#include <hip/hip_runtime.h>
#include <hip/hip_bf16.h>
#include <cmath>

#define NROWS 8192
#define DIM   128
#define KDIM  8192
#define BM    64
#define BN    128
#define BK    64
#define SPLITK 4
#define KCHUNK (KDIM / SPLITK)   // 2048
#define GITERS (KCHUNK / BK)     // 32
#define LDSTRIDE 80              // 64 + 16 pad (shorts); row = 160 B, 16B-aligned

typedef __bf16 bf16_t;
typedef __bf16 bf16x8 __attribute__((ext_vector_type(8)));
typedef __bf16 bf16x4 __attribute__((ext_vector_type(4)));
typedef float  f32x4  __attribute__((ext_vector_type(4)));

// ---------------- fp32 -> bf16 bulk convert (8 elems/thread) ----------------
__global__ void k_cvt(const float* __restrict__ src, bf16_t* __restrict__ dst) {
    size_t i = ((size_t)blockIdx.x * 256 + threadIdx.x) * 8;
    float4 a = *(const float4*)(src + i);
    float4 b = *(const float4*)(src + i + 4);
    bf16x8 v;
    v[0] = (bf16_t)a.x; v[1] = (bf16_t)a.y; v[2] = (bf16_t)a.z; v[3] = (bf16_t)a.w;
    v[4] = (bf16_t)b.x; v[5] = (bf16_t)b.y; v[6] = (bf16_t)b.z; v[7] = (bf16_t)b.w;
    *(bf16x8*)(dst + i) = v;
}

// ------------- theta: transpose to [k][o][i], scale by c_k, bf16 ------------
__global__ void k_theta(const float* __restrict__ th, bf16_t* __restrict__ out,
                        float c0, float c1, float c2, float c3, float c4) {
    int idx = blockIdx.x * 256 + threadIdx.x;          // 81920 total
    int k = idx >> 14;
    int o = (idx >> 7) & 127;
    int i = idx & 127;
    float c = (k == 0) ? c0 : (k == 1) ? c1 : (k == 2) ? c2 : (k == 3) ? c3 : c4;
    out[idx] = (bf16_t)(c * th[(k << 14) + (i << 7) + o]);
}

// ---------------- main GEMM: partial[s] = L[:, chunk] @ B[chunk, :] ----------
// MODE 0: A is bf16. MODE 1: A is fp32 (convert in-register).
// MODE 2: A is fp32, convert, and also write bf16 A back to Lbf_out.
template <int MODE>
__global__ __launch_bounds__(256, 2)
void k_gemm(const void* __restrict__ Ap, const bf16_t* __restrict__ B,
            float* __restrict__ partial, bf16_t* __restrict__ Lbf_out) {
    __shared__ __align__(16) bf16_t As[BM * LDSTRIDE];
    __shared__ __align__(16) bf16_t Bs[BN * LDSTRIDE];

    const int t      = threadIdx.x;
    const int mTile  = blockIdx.x & 127;
    const int s      = blockIdx.x >> 7;
    const int mb     = mTile * BM;
    const int k0base = s * KCHUNK;
    const int wave = t >> 6, lane = t & 63;
    const int wM = (wave & 1) * 32;
    const int wN = (wave >> 1) * 64;
    const int lm = lane & 15, lk = lane >> 4;

    const int arow = t >> 3;     // + rep*32
    const int asc  = t & 7;
    const int bkl  = t & 63;
    const int bn8  = t >> 6;     // + rep*4

    f32x4 acc[2][4];
#pragma unroll
    for (int a = 0; a < 2; ++a)
#pragma unroll
        for (int b = 0; b < 4; ++b) acc[a][b] = (f32x4)0.0f;

    bf16x8 aR[2];
    float4 aRf[2][2];
    bf16x8 bR[4];

    auto loadT = [&](int kk) {
        const int k0 = k0base + kk * BK;
#pragma unroll
        for (int rep = 0; rep < 2; ++rep) {
            const int r = rep * 32 + arow;
            if (MODE == 0) {
                aR[rep] = *(const bf16x8*)((const bf16_t*)Ap +
                            (size_t)(mb + r) * KDIM + k0 + asc * 8);
            } else {
                const float* base = (const float*)Ap +
                            (size_t)(mb + r) * KDIM + k0 + asc * 8;
                aRf[rep][0] = *(const float4*)base;
                aRf[rep][1] = *(const float4*)(base + 4);
            }
        }
#pragma unroll
        for (int rep = 0; rep < 4; ++rep) {
            const int n8 = rep * 4 + bn8;
            bR[rep] = *(const bf16x8*)(B + (size_t)(k0 + bkl) * DIM + n8 * 8);
        }
    };

    auto storeT = [&](int kk) {
        const int k0 = k0base + kk * BK;
#pragma unroll
        for (int rep = 0; rep < 2; ++rep) {
            const int r = rep * 32 + arow;
            bf16x8 v;
            if (MODE == 0) {
                v = aR[rep];
            } else {
                v[0] = (bf16_t)aRf[rep][0].x; v[1] = (bf16_t)aRf[rep][0].y;
                v[2] = (bf16_t)aRf[rep][0].z; v[3] = (bf16_t)aRf[rep][0].w;
                v[4] = (bf16_t)aRf[rep][1].x; v[5] = (bf16_t)aRf[rep][1].y;
                v[6] = (bf16_t)aRf[rep][1].z; v[7] = (bf16_t)aRf[rep][1].w;
                if (MODE == 2)
                    *(bf16x8*)(Lbf_out + (size_t)(mb + r) * KDIM + k0 + asc * 8) = v;
            }
            *(bf16x8*)(&As[r * LDSTRIDE + asc * 8]) = v;
        }
#pragma unroll
        for (int rep = 0; rep < 4; ++rep) {
            const int n8 = rep * 4 + bn8;
            bf16x8 v = bR[rep];
#pragma unroll
            for (int q = 0; q < 8; ++q)
                Bs[(n8 * 8 + q) * LDSTRIDE + bkl] = v[q];
        }
    };

    loadT(0);
    for (int kk = 0; kk < GITERS; ++kk) {
        __syncthreads();
        storeT(kk);
        __syncthreads();
        if (kk + 1 < GITERS) loadT(kk + 1);
#pragma unroll
        for (int ko = 0; ko < 2; ++ko) {
            bf16x8 af[2], bfr[4];
#pragma unroll
            for (int tm = 0; tm < 2; ++tm)
                af[tm] = *(const bf16x8*)(&As[(wM + tm * 16 + lm) * LDSTRIDE +
                                              (ko * 4 + lk) * 8]);
#pragma unroll
            for (int tn = 0; tn < 4; ++tn)
                bfr[tn] = *(const bf16x8*)(&Bs[(wN + tn * 16 + lm) * LDSTRIDE +
                                               (ko * 4 + lk) * 8]);
#pragma unroll
            for (int tm = 0; tm < 2; ++tm)
#pragma unroll
                for (int tn = 0; tn < 4; ++tn)
                    acc[tm][tn] = __builtin_amdgcn_mfma_f32_16x16x32_bf16(
                        af[tm], bfr[tn], acc[tm][tn], 0, 0, 0);
        }
    }

    float* pOut = partial + (size_t)s * NROWS * DIM;
#pragma unroll
    for (int tm = 0; tm < 2; ++tm)
#pragma unroll
        for (int tn = 0; tn < 4; ++tn)
#pragma unroll
            for (int r = 0; r < 4; ++r) {
                const int row = mb + wM + tm * 16 + lk * 4 + r;
                const int col = wN + tn * 16 + lm;
                pOut[(size_t)row * DIM + col] = acc[tm][tn][r];
            }
}

// ------- combine: y = sum(partials); T = first ? y : 2y - prev; emit --------
__global__ void k_combine(const float* __restrict__ p, const float* __restrict__ prev,
                          float* __restrict__ f32dst, bf16_t* __restrict__ bfdst,
                          int first) {
    const size_t S = (size_t)NROWS * DIM;
    size_t i = ((size_t)blockIdx.x * 256 + threadIdx.x) * 4;
    float4 a = *(const float4*)(p + i);
    float4 b = *(const float4*)(p + S + i);
    float4 c = *(const float4*)(p + 2 * S + i);
    float4 d = *(const float4*)(p + 3 * S + i);
    float4 y;
    y.x = a.x + b.x + c.x + d.x;
    y.y = a.y + b.y + c.y + d.y;
    y.z = a.z + b.z + c.z + d.z;
    y.w = a.w + b.w + c.w + d.w;
    if (!first) {
        float4 pv = *(const float4*)(prev + i);
        y.x = 2.0f * y.x - pv.x;
        y.y = 2.0f * y.y - pv.y;
        y.z = 2.0f * y.z - pv.z;
        y.w = 2.0f * y.w - pv.w;
    }
    if (f32dst) *(float4*)(f32dst + i) = y;
    bf16x4 o;
    o[0] = (bf16_t)y.x; o[1] = (bf16_t)y.y; o[2] = (bf16_t)y.z; o[3] = (bf16_t)y.w;
    *(bf16x4*)(bfdst + i) = o;
}

// ------- projection: out = sum_seg Tbf[seg] @ thT[seg]^T (c_k pre-folded) ----
__global__ __launch_bounds__(256, 2)
void k_proj(const bf16_t* __restrict__ T, const bf16_t* __restrict__ W,
            float* __restrict__ out) {
    __shared__ __align__(16) bf16_t As[BM * LDSTRIDE];
    __shared__ __align__(16) bf16_t Bs[BN * LDSTRIDE];

    const int t  = threadIdx.x;
    const int mb = blockIdx.x * BM;
    const int wave = t >> 6, lane = t & 63;
    const int wM = (wave & 1) * 32;
    const int wN = (wave >> 1) * 64;
    const int lm = lane & 15, lk = lane >> 4;
    const int arow = t >> 3;
    const int asc  = t & 7;
    const size_t S = (size_t)NROWS * DIM;

    f32x4 acc[2][4];
#pragma unroll
    for (int a = 0; a < 2; ++a)
#pragma unroll
        for (int b = 0; b < 4; ++b) acc[a][b] = (f32x4)0.0f;

    bf16x8 aR[2], bR[4];

    auto loadT = [&](int it) {
        const int seg = it >> 1;
        const int h   = (it & 1) * 64;
#pragma unroll
        for (int rep = 0; rep < 2; ++rep) {
            const int r = rep * 32 + arow;
            aR[rep] = *(const bf16x8*)(T + (size_t)seg * S +
                        (size_t)(mb + r) * DIM + h + asc * 8);
        }
#pragma unroll
        for (int rep = 0; rep < 4; ++rep) {
            const int o = rep * 32 + arow;
            bR[rep] = *(const bf16x8*)(W + seg * 16384 + o * 128 + h + asc * 8);
        }
    };
    auto storeT = [&]() {
#pragma unroll
        for (int rep = 0; rep < 2; ++rep) {
            const int r = rep * 32 + arow;
            *(bf16x8*)(&As[r * LDSTRIDE + asc * 8]) = aR[rep];
        }
#pragma unroll
        for (int rep = 0; rep < 4; ++rep) {
            const int o = rep * 32 + arow;
            *(bf16x8*)(&Bs[o * LDSTRIDE + asc * 8]) = bR[rep];
        }
    };

    loadT(0);
    for (int it = 0; it < 10; ++it) {
        __syncthreads();
        storeT();
        __syncthreads();
        if (it + 1 < 10) loadT(it + 1);
#pragma unroll
        for (int ko = 0; ko < 2; ++ko) {
            bf16x8 af[2], bfr[4];
#pragma unroll
            for (int tm = 0; tm < 2; ++tm)
                af[tm] = *(const bf16x8*)(&As[(wM + tm * 16 + lm) * LDSTRIDE +
                                              (ko * 4 + lk) * 8]);
#pragma unroll
            for (int tn = 0; tn < 4; ++tn)
                bfr[tn] = *(const bf16x8*)(&Bs[(wN + tn * 16 + lm) * LDSTRIDE +
                                               (ko * 4 + lk) * 8]);
#pragma unroll
            for (int tm = 0; tm < 2; ++tm)
#pragma unroll
                for (int tn = 0; tn < 4; ++tn)
                    acc[tm][tn] = __builtin_amdgcn_mfma_f32_16x16x32_bf16(
                        af[tm], bfr[tn], acc[tm][tn], 0, 0, 0);
        }
    }
#pragma unroll
    for (int tm = 0; tm < 2; ++tm)
#pragma unroll
        for (int tn = 0; tn < 4; ++tn)
#pragma unroll
            for (int r = 0; r < 4; ++r) {
                const int row = mb + wM + tm * 16 + lk * 4 + r;
                const int col = wN + tn * 16 + lm;
                out[(size_t)row * DIM + col] = acc[tm][tn][r];
            }
}

extern "C" void kernel_launch(void* const* d_in, const int* in_sizes, int n_in,
                              void* d_out, int out_size, void* d_ws, size_t ws_size,
                              hipStream_t stream) {
    const float* x  = nullptr;
    const float* L  = nullptr;
    const float* th = nullptr;
    for (int i = 0; i < n_in; ++i) {
        if (in_sizes[i] == NROWS * KDIM)      L  = (const float*)d_in[i];
        else if (in_sizes[i] == NROWS * DIM)  x  = (const float*)d_in[i];
        else if (in_sizes[i] == 5 * DIM * DIM) th = (const float*)d_in[i];
    }
    float* out = (float*)d_out;

    const size_t S = (size_t)NROWS * DIM;          // 1048576 elems
    char* ws = (char*)d_ws;
    size_t off = 0;
    auto alloc = [&](size_t bytes) {
        void* p = ws + off;
        off = (off + bytes + 255) & ~(size_t)255;
        return p;
    };
    bf16_t* Tbf     = (bf16_t*)alloc(5 * S * 2);       // [5][N][128] bf16
    float*  Tf32    = (float*)alloc(2 * S * 4);        // ping-pong fp32 T state
    bf16_t* thT     = (bf16_t*)alloc(5 * 128 * 128 * 2);
    float*  partial = (float*)alloc(SPLITK * S * 4);
    const size_t baseNeed = off;
    bf16_t* Lbf = (bf16_t*)(ws + off);
    const bool useLbf = (off + (size_t)NROWS * KDIM * 2) <= ws_size;
    if (baseNeed > ws_size) return;  // cannot run without minimal scratch

    // Chebyshev-Gauss coefficients, c_k = (2/5) exp(-0.5 cos(pi (k+.5)/5))
    float c[5];
    for (int k = 0; k < 5; ++k)
        c[k] = (float)((2.0 / 5.0) * exp(-0.5 * cos(M_PI * (k + 0.5) / 5.0)));

    dim3 blk(256);
    k_cvt<<<512, blk, 0, stream>>>(x, Tbf);                      // T0 = bf16(x)
    k_theta<<<320, blk, 0, stream>>>(th, thT, c[0], c[1], c[2], c[3], c[4]);

    for (int j = 1; j <= 4; ++j) {
        const bf16_t* Bj = Tbf + (size_t)(j - 1) * S;
        if (useLbf) {
            if (j == 1)
                k_gemm<2><<<512, blk, 0, stream>>>(L, Bj, partial, Lbf);
            else
                k_gemm<0><<<512, blk, 0, stream>>>(Lbf, Bj, partial, nullptr);
        } else {
            k_gemm<1><<<512, blk, 0, stream>>>(L, Bj, partial, nullptr);
        }
        const float* prev = nullptr;
        float* fdst = nullptr;
        if (j == 1)      { fdst = Tf32 + S; }                 // T1 -> slot1
        else if (j == 2) { prev = x;        fdst = Tf32; }    // T2 -> slot0
        else if (j == 3) { prev = Tf32 + S; fdst = Tf32 + S; } // T3 -> slot1
        else             { prev = Tf32;     fdst = nullptr; }  // T4: bf16 only
        k_combine<<<1024, blk, 0, stream>>>(partial, prev, fdst,
                                            Tbf + (size_t)j * S, j == 1 ? 1 : 0);
    }
    k_proj<<<128, blk, 0, stream>>>(Tbf, thT, out);
}

// Round 2
// 604.067 us; speedup vs baseline: 1.0027x; 1.0027x over previous
//
#include <hip/hip_runtime.h>
#include <hip/hip_bf16.h>
#include <cmath>

#define NROWS 8192
#define DIM   128
#define KDIM  8192
#define BM    64
#define BN    128
#define BK    64
#define SPLITK 8
#define KCHUNK (KDIM / SPLITK)   // 1024
#define GITERS (KCHUNK / BK)     // 16
#define LDSTRIDE 80              // proj kernel only

typedef __bf16 bf16_t;
typedef __bf16 bf16x8 __attribute__((ext_vector_type(8)));
typedef __bf16 bf16x4 __attribute__((ext_vector_type(4)));
typedef float  f32x4  __attribute__((ext_vector_type(4)));

__device__ __forceinline__ void async16(const void* g, void* l) {
    __builtin_amdgcn_global_load_lds(
        (const __attribute__((address_space(1))) unsigned int*)g,
        (__attribute__((address_space(3))) unsigned int*)l, 16, 0, 0);
}

// ---------------- fp32 L -> bf16 L (pure streaming convert) -----------------
__global__ void k_cvtL(const float* __restrict__ src, bf16_t* __restrict__ dst) {
    size_t i = ((size_t)blockIdx.x * 256 + threadIdx.x) * 8;
    float4 a = *(const float4*)(src + i);
    float4 b = *(const float4*)(src + i + 4);
    bf16x8 v;
    v[0] = (bf16_t)a.x; v[1] = (bf16_t)a.y; v[2] = (bf16_t)a.z; v[3] = (bf16_t)a.w;
    v[4] = (bf16_t)b.x; v[5] = (bf16_t)b.y; v[6] = (bf16_t)b.z; v[7] = (bf16_t)b.w;
    *(bf16x8*)(dst + i) = v;
}

// ------------- theta: transpose to [k][o][i], scale by c_k, bf16 ------------
__global__ void k_theta(const float* __restrict__ th, bf16_t* __restrict__ out,
                        float c0, float c1, float c2, float c3, float c4) {
    int idx = blockIdx.x * 256 + threadIdx.x;          // 81920 total
    int k = idx >> 14;
    int o = (idx >> 7) & 127;
    int i = idx & 127;
    float c = (k == 0) ? c0 : (k == 1) ? c1 : (k == 2) ? c2 : (k == 3) ? c3 : c4;
    out[idx] = (bf16_t)(c * th[(k << 14) + (i << 7) + o]);
}

// ------------- GEMM: partial[s] = Lbf[:, chunk_s] @ Bt[chunk_s, :]^T --------
// A row-major [8192][8192] bf16; Bt k-major [128 feat][8192 node] bf16.
// Staged via global_load_lds(16) with XOR chunk swizzle; double-buffered.
__global__ __launch_bounds__(256, 3)
void k_gemm(const bf16_t* __restrict__ A, const bf16_t* __restrict__ Bt,
            float* __restrict__ partial) {
    __shared__ __align__(16) bf16_t As[2][BM * BK];   // 8 KB each
    __shared__ __align__(16) bf16_t Bs[2][BN * BK];   // 16 KB each

    const int t     = threadIdx.x;
    const int mTile = blockIdx.x & 127;
    const int s     = blockIdx.x >> 7;
    const int mb    = mTile * BM;
    const int k0base = s * KCHUNK;
    const int wave = t >> 6, lane = t & 63;
    const int wM = (wave & 1) * 32;
    const int wN = (wave >> 1) * 64;
    const int lm = lane & 15, lk = lane >> 4;
    const int lrow = lane >> 3;            // 0..7
    const int lsrc = (lane & 7) ^ lrow;    // XOR-swizzled source chunk

    f32x4 acc[2][4];
#pragma unroll
    for (int a = 0; a < 2; ++a)
#pragma unroll
        for (int b = 0; b < 4; ++b) acc[a][b] = (f32x4)0.0f;

    auto stage = [&](int kk, int buf) {
        const int k0 = k0base + kk * BK;
#pragma unroll
        for (int i = 0; i < 2; ++i) {
            const int r = wave * 16 + i * 8 + lrow;
            async16(A + (size_t)(mb + r) * KDIM + k0 + lsrc * 8,
                    &As[buf][(wave * 16 + i * 8) * BK]);
        }
#pragma unroll
        for (int i = 0; i < 4; ++i) {
            const int n = wave * 32 + i * 8 + lrow;
            async16(Bt + (size_t)n * KDIM + k0 + lsrc * 8,
                    &Bs[buf][(wave * 32 + i * 8) * BK]);
        }
    };

    stage(0, 0);
    __syncthreads();
    for (int kk = 0; kk < GITERS; ++kk) {
        const int buf = kk & 1;
        if (kk + 1 < GITERS) stage(kk + 1, buf ^ 1);
#pragma unroll
        for (int ko = 0; ko < 2; ++ko) {
            bf16x8 af[2], bfr[4];
            const int csX = (ko * 4 + lk) ^ (lm & 7);
#pragma unroll
            for (int tm = 0; tm < 2; ++tm) {
                const int r = wM + tm * 16 + lm;
                af[tm] = *(const bf16x8*)(&As[buf][r * BK + csX * 8]);
            }
#pragma unroll
            for (int tn = 0; tn < 4; ++tn) {
                const int n = wN + tn * 16 + lm;
                bfr[tn] = *(const bf16x8*)(&Bs[buf][n * BK + csX * 8]);
            }
#pragma unroll
            for (int tm = 0; tm < 2; ++tm)
#pragma unroll
                for (int tn = 0; tn < 4; ++tn)
                    acc[tm][tn] = __builtin_amdgcn_mfma_f32_16x16x32_bf16(
                        af[tm], bfr[tn], acc[tm][tn], 0, 0, 0);
        }
        __syncthreads();
    }

    float* pOut = partial + (size_t)s * NROWS * DIM;
#pragma unroll
    for (int tm = 0; tm < 2; ++tm)
#pragma unroll
        for (int tn = 0; tn < 4; ++tn)
#pragma unroll
            for (int r = 0; r < 4; ++r) {
                const int row = mb + wM + tm * 16 + lk * 4 + r;
                const int col = wN + tn * 16 + lm;
                pOut[(size_t)row * DIM + col] = acc[tm][tn][r];
            }
}

// ---- combine: y = sum(partials) [or x]; recurrence; emit fp32/Tbf/Bt -------
// MODE 0: y = src (fp32 x).  MODE 1: y = sum_s partial.  MODE 2: 2*sum - prev.
// Writes: f32dst (opt), tbf row-major [node][feat], bt k-major [feat][node] (opt).
template <int MODE>
__global__ void k_combine(const float* __restrict__ src, const float* __restrict__ prev,
                          float* __restrict__ f32dst, bf16_t* __restrict__ tbf,
                          bf16_t* __restrict__ bt) {
    __shared__ bf16_t tl[128 * 24];      // [feat][16 node + pad]
    const size_t S = (size_t)NROWS * DIM;
    const int t  = threadIdx.x;
    const int n0 = blockIdx.x * 16;
    const int nl = t >> 4;               // 0..15 node within tile
    const int dp = (t & 15) * 8;         // 0..120 feature offset
    const int n  = n0 + nl;

    float y[8];
    if (MODE == 0) {
        float4 a = *(const float4*)(src + (size_t)n * DIM + dp);
        float4 b = *(const float4*)(src + (size_t)n * DIM + dp + 4);
        y[0] = a.x; y[1] = a.y; y[2] = a.z; y[3] = a.w;
        y[4] = b.x; y[5] = b.y; y[6] = b.z; y[7] = b.w;
    } else {
#pragma unroll
        for (int j = 0; j < 8; ++j) y[j] = 0.0f;
#pragma unroll
        for (int ss = 0; ss < SPLITK; ++ss) {
            const float* p = src + (size_t)ss * S + (size_t)n * DIM + dp;
            float4 a = *(const float4*)p;
            float4 b = *(const float4*)(p + 4);
            y[0] += a.x; y[1] += a.y; y[2] += a.z; y[3] += a.w;
            y[4] += b.x; y[5] += b.y; y[6] += b.z; y[7] += b.w;
        }
        if (MODE == 2) {
            float4 a = *(const float4*)(prev + (size_t)n * DIM + dp);
            float4 b = *(const float4*)(prev + (size_t)n * DIM + dp + 4);
            y[0] = 2.0f * y[0] - a.x; y[1] = 2.0f * y[1] - a.y;
            y[2] = 2.0f * y[2] - a.z; y[3] = 2.0f * y[3] - a.w;
            y[4] = 2.0f * y[4] - b.x; y[5] = 2.0f * y[5] - b.y;
            y[6] = 2.0f * y[6] - b.z; y[7] = 2.0f * y[7] - b.w;
        }
    }
    if (f32dst) {
        float4 a, b;
        a.x = y[0]; a.y = y[1]; a.z = y[2]; a.w = y[3];
        b.x = y[4]; b.y = y[5]; b.z = y[6]; b.w = y[7];
        *(float4*)(f32dst + (size_t)n * DIM + dp) = a;
        *(float4*)(f32dst + (size_t)n * DIM + dp + 4) = b;
    }
    bf16x8 v;
#pragma unroll
    for (int j = 0; j < 8; ++j) v[j] = (bf16_t)y[j];
    *(bf16x8*)(tbf + (size_t)n * DIM + dp) = v;
    if (bt) {
#pragma unroll
        for (int j = 0; j < 8; ++j) tl[(dp + j) * 24 + nl] = v[j];
        __syncthreads();
        const int d = t >> 1, h = (t & 1) * 8;
        bf16x8 w = *(const bf16x8*)(&tl[d * 24 + h]);
        *(bf16x8*)(bt + (size_t)d * NROWS + n0 + h) = w;
    }
}

// ------- projection: out = sum_seg Tbf[seg] @ thT[seg]^T (c_k pre-folded) ----
__global__ __launch_bounds__(256, 2)
void k_proj(const bf16_t* __restrict__ T, const bf16_t* __restrict__ W,
            float* __restrict__ out) {
    __shared__ __align__(16) bf16_t As[BM * LDSTRIDE];
    __shared__ __align__(16) bf16_t Bs[BN * LDSTRIDE];

    const int t  = threadIdx.x;
    const int mb = blockIdx.x * BM;
    const int wave = t >> 6, lane = t & 63;
    const int wM = (wave & 1) * 32;
    const int wN = (wave >> 1) * 64;
    const int lm = lane & 15, lk = lane >> 4;
    const int arow = t >> 3;
    const int asc  = t & 7;
    const size_t S = (size_t)NROWS * DIM;

    f32x4 acc[2][4];
#pragma unroll
    for (int a = 0; a < 2; ++a)
#pragma unroll
        for (int b = 0; b < 4; ++b) acc[a][b] = (f32x4)0.0f;

    bf16x8 aR[2], bR[4];

    auto loadT = [&](int it) {
        const int seg = it >> 1;
        const int h   = (it & 1) * 64;
#pragma unroll
        for (int rep = 0; rep < 2; ++rep) {
            const int r = rep * 32 + arow;
            aR[rep] = *(const bf16x8*)(T + (size_t)seg * S +
                        (size_t)(mb + r) * DIM + h + asc * 8);
        }
#pragma unroll
        for (int rep = 0; rep < 4; ++rep) {
            const int o = rep * 32 + arow;
            bR[rep] = *(const bf16x8*)(W + seg * 16384 + o * 128 + h + asc * 8);
        }
    };
    auto storeT = [&]() {
#pragma unroll
        for (int rep = 0; rep < 2; ++rep) {
            const int r = rep * 32 + arow;
            *(bf16x8*)(&As[r * LDSTRIDE + asc * 8]) = aR[rep];
        }
#pragma unroll
        for (int rep = 0; rep < 4; ++rep) {
            const int o = rep * 32 + arow;
            *(bf16x8*)(&Bs[o * LDSTRIDE + asc * 8]) = bR[rep];
        }
    };

    loadT(0);
    for (int it = 0; it < 10; ++it) {
        __syncthreads();
        storeT();
        __syncthreads();
        if (it + 1 < 10) loadT(it + 1);
#pragma unroll
        for (int ko = 0; ko < 2; ++ko) {
            bf16x8 af[2], bfr[4];
#pragma unroll
            for (int tm = 0; tm < 2; ++tm)
                af[tm] = *(const bf16x8*)(&As[(wM + tm * 16 + lm) * LDSTRIDE +
                                              (ko * 4 + lk) * 8]);
#pragma unroll
            for (int tn = 0; tn < 4; ++tn)
                bfr[tn] = *(const bf16x8*)(&Bs[(wN + tn * 16 + lm) * LDSTRIDE +
                                               (ko * 4 + lk) * 8]);
#pragma unroll
            for (int tm = 0; tm < 2; ++tm)
#pragma unroll
                for (int tn = 0; tn < 4; ++tn)
                    acc[tm][tn] = __builtin_amdgcn_mfma_f32_16x16x32_bf16(
                        af[tm], bfr[tn], acc[tm][tn], 0, 0, 0);
        }
    }
#pragma unroll
    for (int tm = 0; tm < 2; ++tm)
#pragma unroll
        for (int tn = 0; tn < 4; ++tn)
#pragma unroll
            for (int r = 0; r < 4; ++r) {
                const int row = mb + wM + tm * 16 + lk * 4 + r;
                const int col = wN + tn * 16 + lm;
                out[(size_t)row * DIM + col] = acc[tm][tn][r];
            }
}

extern "C" void kernel_launch(void* const* d_in, const int* in_sizes, int n_in,
                              void* d_out, int out_size, void* d_ws, size_t ws_size,
                              hipStream_t stream) {
    const float* x  = nullptr;
    const float* L  = nullptr;
    const float* th = nullptr;
    for (int i = 0; i < n_in; ++i) {
        if (in_sizes[i] == NROWS * KDIM)       L  = (const float*)d_in[i];
        else if (in_sizes[i] == NROWS * DIM)   x  = (const float*)d_in[i];
        else if (in_sizes[i] == 5 * DIM * DIM) th = (const float*)d_in[i];
    }
    float* out = (float*)d_out;

    const size_t S = (size_t)NROWS * DIM;          // 1048576 elems
    char* ws = (char*)d_ws;
    size_t off = 0;
    auto alloc = [&](size_t bytes) {
        void* p = ws + off;
        off = (off + bytes + 255) & ~(size_t)255;
        return p;
    };
    bf16_t* Tbf     = (bf16_t*)alloc(5 * S * 2);        // [5][node][feat]
    bf16_t* Bt      = (bf16_t*)alloc(5 * S * 2);        // [5][feat][node]
    float*  Tf32    = (float*)alloc(2 * S * 4);         // fp32 recurrence state
    bf16_t* thT     = (bf16_t*)alloc(5 * 128 * 128 * 2);
    float*  partial = (float*)alloc((size_t)SPLITK * S * 4);
    bf16_t* Lbf     = (bf16_t*)alloc((size_t)NROWS * KDIM * 2);
    if (off > ws_size) return;

    float c[5];
    for (int k = 0; k < 5; ++k)
        c[k] = (float)((2.0 / 5.0) * exp(-0.5 * cos(M_PI * (k + 0.5) / 5.0)));

    dim3 blk(256);
    k_cvtL<<<32768, blk, 0, stream>>>(L, Lbf);
    k_combine<0><<<512, blk, 0, stream>>>(x, nullptr, nullptr, Tbf, Bt);
    k_theta<<<320, blk, 0, stream>>>(th, thT, c[0], c[1], c[2], c[3], c[4]);

    for (int j = 1; j <= 4; ++j) {
        k_gemm<<<1024, blk, 0, stream>>>(Lbf, Bt + (size_t)(j - 1) * S, partial);
        bf16_t* tbf = Tbf + (size_t)j * S;
        bf16_t* bt  = (j < 4) ? Bt + (size_t)j * S : nullptr;
        if (j == 1)
            k_combine<1><<<512, blk, 0, stream>>>(partial, nullptr, Tf32 + S, tbf, bt);
        else if (j == 2)
            k_combine<2><<<512, blk, 0, stream>>>(partial, x, Tf32, tbf, bt);
        else if (j == 3)
            k_combine<2><<<512, blk, 0, stream>>>(partial, Tf32 + S, Tf32 + S, tbf, bt);
        else
            k_combine<2><<<512, blk, 0, stream>>>(partial, Tf32, nullptr, tbf, nullptr);
    }
    k_proj<<<128, blk, 0, stream>>>(Tbf, thT, out);
}